// Round 1
// baseline (202.413 us; speedup 1.0000x reference)
//
#include <hip/hip_runtime.h>
#include <hip/hip_bf16.h>
#include <stdint.h>

#define KTAPS 9
#define C_IN 128
#define C_OUT 256
#define HW 56
#define PLANE 3136           // 56*56
#define BATCH 32
#define NPX (BATCH * PLANE)  // 100352
#define KTOT 1152            // 9*128
#define PXB 64               // pixels per block (3136 % 64 == 0 -> block never crosses image)
#define NBLK (NPX / PXB)     // 1568 = 8 * 196
#define BLK_PER_XCD (NBLK / 8)

typedef __attribute__((ext_vector_type(8))) _Float16 f16x8;
typedef __attribute__((ext_vector_type(4))) float f32x4;

static __device__ __forceinline__ uint16_t f2h(float f) {
    _Float16 h = (_Float16)f;
    uint16_t u;
    __builtin_memcpy(&u, &h, 2);
    return u;
}

// ---------------- P1: feature NCHW fp32 -> NHWC f16 ----------------
__global__ void k_feat_nhwc(const float* __restrict__ f, unsigned short* __restrict__ fws) {
    __shared__ float tile[C_IN * 57];
    int blk = blockIdx.x;              // b*56 + y
    int b = blk / HW, y = blk % HW;
    const float* src = f + (size_t)b * C_IN * PLANE + y * HW;
    for (int i = threadIdx.x; i < C_IN * HW; i += 256) {
        int c = i / HW, x = i % HW;
        tile[c * 57 + x] = src[(size_t)c * PLANE + x];
    }
    __syncthreads();
    unsigned short* dst = fws + (size_t)blk * HW * C_IN;
    for (int j = threadIdx.x; j < HW * C_IN; j += 256) {
        int x = j >> 7, c = j & 127;
        dst[j] = f2h(tile[c * 57 + x]);
    }
}

// ---------------- P2: weight [OC][IC][3][3] fp32 -> W2[oc][t*128+ic] f16 ----------------
__global__ void k_weight(const float* __restrict__ w, unsigned short* __restrict__ W2) {
    int idx = blockIdx.x * 256 + threadIdx.x;
    if (idx >= C_OUT * KTOT) return;
    int oc = idx / KTOT, r = idx % KTOT;
    int t = r >> 7, ic = r & 127;
    int j = t / 3, i = t % 3;
    W2[idx] = f2h(w[((oc * C_IN + ic) * 3 + j) * 3 + i]);
}

// ---------------- P3: offset [B][18][x][y] -> sxy[tc][px] unnormalized coords ----------------
__global__ void k_coords(const float* __restrict__ off, float* __restrict__ sxy) {
    __shared__ float tile[HW * 57];
    int blk = blockIdx.x;              // b*18 + tc
    int b = blk / 18, tc = blk % 18;
    const float* src = off + (size_t)blk * PLANE;
    for (int i = threadIdx.x; i < PLANE; i += 256) {
        int xx = i / HW, yy = i % HW;
        tile[xx * 57 + yy] = src[i];
    }
    __syncthreads();
    float* dst = sxy + (size_t)tc * NPX + (size_t)b * PLANE;
    bool isx = (tc & 1) == 0;
    for (int p = threadIdx.x; p < PLANE; p += 256) {
        int y = p / HW, x = p % HW;
        float v = tile[x * 57 + y];
        float a = isx ? ((float)x - 27.5f) * (1.0f / 27.5f)
                      : ((float)y - 27.5f) * (1.0f / 27.5f);
        dst[p] = (v + a + 1.0f) * 28.0f - 0.5f;
    }
}

// ---------------- P4: fused sample + GEMM ----------------
// block: 64 px x 256 oc, 4 waves (wave w: oc [64w,64w+64), samples px [16w,16w+16))
// Per tap: 4 rounds of { prefetch A(next ks) ; issue 4 sample loads (1 px/lane) ;
//                        16 MFMA ; finish (combine + Vs write) }.
// Register diet vs prior version: acc 4x4 (64 AGPR), sv[4] (16 VGPR), no fbase LDS
// (3136 % 64 == 0 -> per-block feature base is a scalar). Target 3 waves/SIMD.
__global__ __launch_bounds__(256, 3) void k_main(const unsigned short* __restrict__ fws,
                                                 const unsigned short* __restrict__ W2,
                                                 const float* __restrict__ sxy,
                                                 float* __restrict__ out) {
    __shared__ __align__(16) unsigned char Vs[2][PXB * 256];  // 2 x (64 px x 128 k f16), XOR-swizzled
    __shared__ float cs[18][PXB];
    const int tid = threadIdx.x;
    const int wave = tid >> 6, lane = tid & 63;
    const int l16 = lane & 15, grp = lane >> 4;
    const int bid = blockIdx.x;
    const int lbid = (bid & 7) * BLK_PER_XCD + (bid >> 3);    // XCD-chunked swizzle (1568 % 8 == 0)
    const int px0 = lbid * PXB;
    const int fb_s = (px0 / PLANE) * (PLANE * C_IN);          // whole block in one image

    // stage coords
    for (int i = tid; i < 18 * PXB; i += 256) {
        int tc = i >> 6, p = i & (PXB - 1);
        cs[tc][p] = sxy[(size_t)tc * NPX + px0 + p];
    }
    __syncthreads();

    f32x4 acc[4][4];
#pragma unroll
    for (int m = 0; m < 4; m++)
#pragma unroll
        for (int n = 0; n < 4; n++) acc[m][n] = (f32x4)0.0f;

    f16x8 sv[4];       // corner vectors (one pixel per lane-group per round)
    float sw[4];
    f16x8 A[2][4];     // ping-pong weight fragments [slot][mt]

    auto issue1 = [&](int t, int r) {
        int p = wave * 16 + r * 4 + grp;
        float ixv = cs[2 * t][p];
        float iyv = cs[2 * t + 1][p];
        const unsigned short* fb = fws + fb_s;
        float fx0 = floorf(ixv), fy0 = floorf(iyv);
        float wx1 = ixv - fx0, wy1 = iyv - fy0;
        float wx0 = 1.0f - wx1, wy0 = 1.0f - wy1;
        int ix0 = (int)fx0, iy0 = (int)fy0;
        int ix1 = ix0 + 1, iy1 = iy0 + 1;
        float vx0 = ((unsigned)ix0 < HW) ? 1.0f : 0.0f;
        float vx1 = ((unsigned)ix1 < HW) ? 1.0f : 0.0f;
        float vy0 = ((unsigned)iy0 < HW) ? 1.0f : 0.0f;
        float vy1 = ((unsigned)iy1 < HW) ? 1.0f : 0.0f;
        int xc0 = min(max(ix0, 0), HW - 1), xc1 = min(max(ix1, 0), HW - 1);
        int yc0 = min(max(iy0, 0), HW - 1), yc1 = min(max(iy1, 0), HW - 1);
        const unsigned short* r0 = fb + (size_t)(yc0 * HW) * C_IN + l16 * 8;
        const unsigned short* r1 = fb + (size_t)(yc1 * HW) * C_IN + l16 * 8;
        sv[0] = *(const f16x8*)(r0 + xc0 * C_IN);
        sv[1] = *(const f16x8*)(r0 + xc1 * C_IN);
        sv[2] = *(const f16x8*)(r1 + xc0 * C_IN);
        sv[3] = *(const f16x8*)(r1 + xc1 * C_IN);
        sw[0] = wx0 * wy0 * vx0 * vy0;
        sw[1] = wx1 * wy0 * vx1 * vy0;
        sw[2] = wx0 * wy1 * vx0 * vy1;
        sw[3] = wx1 * wy1 * vx1 * vy1;
    };

    auto finish1 = [&](int buf, int r) {
        int p = wave * 16 + r * 4 + grp;
        f16x8 v = sv[0] * (f16x8)(_Float16)sw[0]
                + sv[1] * (f16x8)(_Float16)sw[1]
                + sv[2] * (f16x8)(_Float16)sw[2]
                + sv[3] * (f16x8)(_Float16)sw[3];
        int byteoff = p * 256 + ((l16 * 16) ^ ((p & 7) << 4));
        *(f16x8*)(&Vs[buf][byteoff]) = v;
    };

    auto loadA = [&](int slot, int t, int ks) {
        const unsigned short* wb = W2 + (size_t)(wave * 64 + l16) * KTOT + t * 128 + ks * 32 + grp * 8;
#pragma unroll
        for (int mt = 0; mt < 4; mt++)
            A[slot][mt] = *(const f16x8*)(wb + (size_t)(mt * 16) * KTOT);
    };

    auto gemm_ks = [&](int ks, int buf, int slot) {
        f16x8 bv[4];
#pragma unroll
        for (int nt = 0; nt < 4; nt++) {
            int pxl = nt * 16 + l16;
            int kbyte = ks * 64 + grp * 16;
            bv[nt] = *(const f16x8*)(&Vs[buf][pxl * 256 + (kbyte ^ ((pxl & 7) << 4))]);
        }
#pragma unroll
        for (int mt = 0; mt < 4; mt++)
#pragma unroll
            for (int nt = 0; nt < 4; nt++)
                acc[mt][nt] = __builtin_amdgcn_mfma_f32_16x16x32_f16(A[slot][mt], bv[nt], acc[mt][nt], 0, 0, 0);
    };

    // prologue: weights for (t=0, ks=0), then sample tap 0 into Vs[0]
    loadA(0, 0, 0);
#pragma unroll
    for (int r = 0; r < 4; r++) {
        issue1(0, r);
        finish1(0, r);
    }
    __syncthreads();

    for (int t = 0; t < KTAPS; t++) {
        const int buf = t & 1, nbuf = buf ^ 1;
        const bool more = (t < KTAPS - 1);
        // round 0: uses A[0], prefetches A[1] = (t,1)
        loadA(1, t, 1);
        if (more) issue1(t + 1, 0);
        gemm_ks(0, buf, 0);
        if (more) finish1(nbuf, 0);
        // round 1: uses A[1], prefetches A[0] = (t,2)
        loadA(0, t, 2);
        if (more) issue1(t + 1, 1);
        gemm_ks(1, buf, 1);
        if (more) finish1(nbuf, 1);
        // round 2: uses A[0], prefetches A[1] = (t,3)
        loadA(1, t, 3);
        if (more) issue1(t + 1, 2);
        gemm_ks(2, buf, 0);
        if (more) finish1(nbuf, 2);
        // round 3: uses A[1], prefetches A[0] = (t+1,0)
        if (more) loadA(0, t + 1, 0);
        if (more) issue1(t + 1, 3);
        gemm_ks(3, buf, 1);
        if (more) finish1(nbuf, 3);
        __syncthreads();
    }

    // epilogue: D col = px = nt*16 + l16; D row = oc = wave*64 + mt*16 + grp*4 + r
#pragma unroll
    for (int nt = 0; nt < 4; nt++) {
        int pp0 = px0 + nt * 16;
        int bb = pp0 / PLANE;
        int rr = pp0 - bb * PLANE;
        float* ob = out + (size_t)bb * C_OUT * PLANE + rr + l16;
#pragma unroll
        for (int mt = 0; mt < 4; mt++) {
#pragma unroll
            for (int r = 0; r < 4; r++) {
                int oc = wave * 64 + mt * 16 + grp * 4 + r;
                ob[(size_t)oc * PLANE] = acc[mt][nt][r];
            }
        }
    }
}

extern "C" void kernel_launch(void* const* d_in, const int* in_sizes, int n_in,
                              void* d_out, int out_size, void* d_ws, size_t ws_size,
                              hipStream_t stream) {
    const float* feature = (const float*)d_in[0];
    const float* offset = (const float*)d_in[1];
    const float* weight = (const float*)d_in[2];
    float* out = (float*)d_out;

    char* ws = (char*)d_ws;
    unsigned short* fws = (unsigned short*)ws;                          // 25,690,112 B
    unsigned short* W2 = (unsigned short*)(ws + 25690112);              // 589,824 B
    float* sxy = (float*)(ws + 25690112 + 589824);                      // 7,225,344 B

    k_feat_nhwc<<<BATCH * HW, 256, 0, stream>>>(feature, fws);
    k_weight<<<(C_OUT * KTOT + 255) / 256, 256, 0, stream>>>(weight, W2);
    k_coords<<<BATCH * 18, 256, 0, stream>>>(offset, sxy);
    k_main<<<NBLK, 256, 0, stream>>>(fws, W2, sxy, out);
}